// Round 1
// baseline (2676.199 us; speedup 1.0000x reference)
//
#include <hip/hip_runtime.h>

#define SEQ_T 512
#define BATCH_N 128
#define ISZ 256
#define HSZ 512
#define G4 2048  // 4*HSZ

typedef __attribute__((ext_vector_type(8))) short short8;
typedef __attribute__((ext_vector_type(4))) float f32x4;

__device__ __forceinline__ unsigned short f2bf(float f) {
  unsigned u = __builtin_bit_cast(unsigned, f);
  u = u + 0x7FFFu + ((u >> 16) & 1u);
  return (unsigned short)(u >> 16);
}
__device__ __forceinline__ float bf2f(unsigned short s) {
  unsigned u = ((unsigned)s) << 16;
  return __builtin_bit_cast(float, u);
}
__device__ __forceinline__ float sigm(float x) {
  x = fminf(fmaxf(x, -30.f), 30.f);
  return 1.f / (1.f + __expf(-x));
}
__device__ __forceinline__ float tanh_f(float x) {
  x = fminf(fmaxf(x, -15.f), 15.f);
  float e = __expf(2.f * x);
  return (e - 1.f) / (e + 1.f);
}

// ---------------- prep: f32 -> bf16 weights, bias sum ----------------
__global__ void prep_kernel(const float* __restrict__ Wih_f, const float* __restrict__ Whh_f,
                            const float* __restrict__ bih, const float* __restrict__ bhh,
                            short* __restrict__ Wih_bf, short* __restrict__ Whh_bf,
                            float* __restrict__ bias) {
  int stride = gridDim.x * blockDim.x;
  int i0 = blockIdx.x * blockDim.x + threadIdx.x;
  for (int i = i0; i < G4 * HSZ; i += stride) Whh_bf[i] = (short)f2bf(Whh_f[i]);
  for (int i = i0; i < G4 * ISZ; i += stride) Wih_bf[i] = (short)f2bf(Wih_f[i]);
  for (int i = i0; i < G4; i += stride) bias[i] = bih[i] + bhh[i];
}

// ---------------- phase 1: x_proj GEMM (bf16 MFMA) ----------------
// XP blocked layout per (t_local, grp, jt): 2048 bf16 = 4KB block.
// Within block, element index = tid*8 + m*4 + r matching rec_kernel's
// per-thread fragment (gate=w, j=m*16+hi*4+r, b_loc=lo).
__global__ __launch_bounds__(256) void xproj_kernel(
    const float* __restrict__ x, const short* __restrict__ Wih,
    const float* __restrict__ bias, short* __restrict__ XP,
    int t0, int Tc, int M_TILE) {
  extern __shared__ char smem[];
  short* Xl = (short*)smem;             // [128][256] bf16, swizzled
  short* Wt = (short*)(smem + 65536);   // [64][256] bf16, swizzled
  const int tid = threadIdx.x;
  const int tl = blockIdx.x % Tc;
  const int ms = blockIdx.x / Tc;
  const int t = t0 + tl;
  const int m0 = ms * M_TILE;
  const int w = tid >> 6, lane = tid & 63, lo = lane & 15, hi = lane >> 4;

  for (int idx = tid; idx < BATCH_N * 64; idx += 256) {
    int b = idx >> 6, q = idx & 63;
    const float4 v = *(const float4*)(x + ((size_t)b * SEQ_T + t) * ISZ + q * 4);
    unsigned long long p = (unsigned long long)f2bf(v.x)
        | ((unsigned long long)f2bf(v.y) << 16)
        | ((unsigned long long)f2bf(v.z) << 32)
        | ((unsigned long long)f2bf(v.w) << 48);
    int byte = (b * 512 + q * 8) ^ ((b & 7) << 4);
    *(unsigned long long*)((char*)Xl + byte) = p;
  }
  __syncthreads();

  for (int mi = 0; mi < M_TILE / 64; ++mi) {
    int g0 = m0 + mi * 64;
    for (int idx = tid; idx < 64 * 32; idx += 256) {
      int r = idx >> 5, q = idx & 31;
      short8 v = *(const short8*)(Wih + (size_t)(g0 + r) * ISZ + q * 8);
      int byte = (r * 512 + q * 16) ^ ((r & 7) << 4);
      *(short8*)((char*)Wt + byte) = v;
    }
    __syncthreads();

    f32x4 acc[8];
#pragma unroll
    for (int n = 0; n < 8; ++n) acc[n] = (f32x4){0.f, 0.f, 0.f, 0.f};
    const int rA = w * 16 + lo;
#pragma unroll
    for (int ks = 0; ks < 8; ++ks) {
      int kb = ks * 64 + hi * 16;
      short8 a = *(const short8*)((const char*)Wt + ((rA * 512 + kb) ^ ((rA & 7) << 4)));
#pragma unroll
      for (int n = 0; n < 8; ++n) {
        int rB = n * 16 + lo;
        short8 bb = *(const short8*)((const char*)Xl + ((rB * 512 + kb) ^ ((rB & 7) << 4)));
        acc[n] = __builtin_amdgcn_mfma_f32_16x16x32_bf16(a, bb, acc[n], 0, 0, 0);
      }
    }
    float b4[4];
#pragma unroll
    for (int r = 0; r < 4; ++r) b4[r] = bias[g0 + w * 16 + hi * 4 + r];
#pragma unroll
    for (int n = 0; n < 8; ++n) {
#pragma unroll
      for (int r = 0; r < 4; ++r) {
        int g = g0 + w * 16 + hi * 4 + r;
        float v = acc[n][r] + b4[r];
        int jloc = g & (HSZ - 1);
        int gate = g >> 9;
        int jtl = jloc >> 5;
        int j = jloc & 31;
        size_t blk = ((size_t)tl * 8 + n) * 16 + jtl;
        size_t oidx = blk * 2048 +
            (size_t)(((gate * 4 + ((j >> 2) & 3)) * 16 + lo) * 8 + ((j >> 4) * 4) + (j & 3));
        XP[oidx] = (short)f2bf(v);
      }
    }
    __syncthreads();
  }
}

// ---------------- phase 2: persistent recurrence ----------------
// grid = 128 wgs: grp = bid>>4 (16 batches), jt = bid&15 (32 hidden units).
// Wave w handles gate w (0=i,1=f,2=g,3=o).
__global__ __launch_bounds__(256) void rec_kernel(
    const short* __restrict__ XP, const short* __restrict__ Whh,
    short* __restrict__ hbuf, float* __restrict__ c_ws, float* __restrict__ hfin,
    unsigned int* __restrict__ flags, int t0, int Tc, int Ttot) {
  extern __shared__ char smem[];
  short* Wl = (short*)smem;                        // [128][512] bf16 swizzled (128KB)
  short* Hl = (short*)(smem + 131072);             // [16][512] bf16 swizzled (16KB)
  float* actsL = (float*)(smem + 131072 + 16384);  // [4][32][16] f32 (8KB)
  const int tid = threadIdx.x;
  const int bid = blockIdx.x;
  const int grp = bid >> 4;
  const int jt = bid & 15;
  const int w = tid >> 6, lane = tid & 63, lo = lane & 15, hi = lane >> 4;

  // stage W_hh slice: row r = gate(r>>5)*512 + jt*32 + (r&31)
  for (int idx = tid; idx < 128 * 64; idx += 256) {
    int r = idx >> 6, q = idx & 63;
    int g = (r >> 5) * HSZ + jt * 32 + (r & 31);
    short8 v = *(const short8*)(Whh + (size_t)g * HSZ + q * 8);
    int byte = (r * 1024 + q * 16) ^ ((r & 7) << 4);
    *(short8*)((char*)Wl + byte) = v;
  }
  const int ub = tid >> 4;        // batch_loc 0..15
  const int uj = (tid & 15) * 2;  // j0 (2 consecutive j per thread)
  float2 creg = *(const float2*)(c_ws + (size_t)(grp * 16 + ub) * HSZ + jt * 32 + uj);
  __syncthreads();

  short8 xp_cur;
  {
    size_t blk = ((size_t)0 * 8 + grp) * 16 + jt;
    xp_cur = *(const short8*)(XP + blk * 2048 + tid * 8);
  }

  for (int tl = 0; tl < Tc; ++tl) {
    const int t = t0 + tl;
    if (t > 0 && tid < 16) {
      const unsigned tgt = (unsigned)t;
      while (__hip_atomic_load(&flags[grp * 16 + tid], __ATOMIC_RELAXED,
                               __HIP_MEMORY_SCOPE_AGENT) < tgt) {}
    }
    __syncthreads();
    asm volatile("" ::: "memory");

    // stage h tile (agent-scope loads bypass stale L2; data lives at LLC)
    if (t == 0) {
      for (int idx = tid; idx < 2048; idx += 256) {
        int r = idx >> 7, q = idx & 127;
        int byte = (r * 1024 + q * 8) ^ ((r & 7) << 4);
        *(unsigned long long*)((char*)Hl + byte) = 0ULL;
      }
    } else {
      unsigned long long* hb =
          (unsigned long long*)(hbuf + (size_t)(t & 1) * BATCH_N * HSZ);
      int bl = tid >> 4, seg = tid & 15;
      size_t base = (size_t)(grp * 16 + bl) * (HSZ / 4) + seg * 8;
#pragma unroll
      for (int q = 0; q < 8; ++q) {
        unsigned long long v = __hip_atomic_load(hb + base + q, __ATOMIC_RELAXED,
                                                 __HIP_MEMORY_SCOPE_AGENT);
        int byte = (bl * 1024 + seg * 64 + q * 8) ^ ((bl & 7) << 4);
        *(unsigned long long*)((char*)Hl + byte) = v;
      }
    }
    __syncthreads();

    f32x4 acc0 = {0.f, 0.f, 0.f, 0.f}, acc1 = {0.f, 0.f, 0.f, 0.f};
    const int rA0 = w * 32 + lo;
#pragma unroll
    for (int ks = 0; ks < 16; ++ks) {
      int kb = ks * 64 + hi * 16;
      short8 a0 = *(const short8*)((const char*)Wl + ((rA0 * 1024 + kb) ^ ((rA0 & 7) << 4)));
      short8 a1 = *(const short8*)((const char*)Wl + (((rA0 + 16) * 1024 + kb) ^ ((rA0 & 7) << 4)));
      short8 bf = *(const short8*)((const char*)Hl + ((lo * 1024 + kb) ^ ((lo & 7) << 4)));
      acc0 = __builtin_amdgcn_mfma_f32_16x16x32_bf16(a0, bf, acc0, 0, 0, 0);
      acc1 = __builtin_amdgcn_mfma_f32_16x16x32_bf16(a1, bf, acc1, 0, 0, 0);
    }

    // activations -> LDS
#pragma unroll
    for (int m = 0; m < 2; ++m) {
      f32x4 av = m ? acc1 : acc0;
#pragma unroll
      for (int r = 0; r < 4; ++r) {
        float pre = av[r] + bf2f((unsigned short)xp_cur[m * 4 + r]);
        float a = (w == 2) ? tanh_f(pre) : sigm(pre);
        int j = m * 16 + hi * 4 + r;
        actsL[(w * 32 + j) * 16 + lo] = a;
      }
    }
    if (tl + 1 < Tc) {
      size_t blk = ((size_t)(tl + 1) * 8 + grp) * 16 + jt;
      xp_cur = *(const short8*)(XP + blk * 2048 + tid * 8);
    }
    __syncthreads();

    // c/h update: this thread owns (b=ub, j=uj..uj+1)
    {
      float ig0 = actsL[(0 * 32 + uj) * 16 + ub], fg0 = actsL[(1 * 32 + uj) * 16 + ub];
      float gg0 = actsL[(2 * 32 + uj) * 16 + ub], og0 = actsL[(3 * 32 + uj) * 16 + ub];
      float ig1 = actsL[(0 * 32 + uj + 1) * 16 + ub], fg1 = actsL[(1 * 32 + uj + 1) * 16 + ub];
      float gg1 = actsL[(2 * 32 + uj + 1) * 16 + ub], og1 = actsL[(3 * 32 + uj + 1) * 16 + ub];
      creg.x = fg0 * creg.x + ig0 * gg0;
      creg.y = fg1 * creg.y + ig1 * gg1;
      float h0 = og0 * tanh_f(creg.x);
      float h1 = og1 * tanh_f(creg.y);
      unsigned hp = (unsigned)f2bf(h0) | ((unsigned)f2bf(h1) << 16);
      unsigned* dst = (unsigned*)(hbuf + (size_t)((t + 1) & 1) * BATCH_N * HSZ +
                                  (size_t)(grp * 16 + ub) * HSZ + jt * 32 + uj);
      __hip_atomic_store(dst, hp, __ATOMIC_RELAXED, __HIP_MEMORY_SCOPE_AGENT);
      if (t == Ttot - 1) {
        float2 hv;
        hv.x = h0; hv.y = h1;
        *(float2*)(hfin + (size_t)(grp * 16 + ub) * HSZ + jt * 32 + uj) = hv;
      }
    }
    __syncthreads();  // drains vmcnt before barrier -> h stores globally visible
    if (tid == 0)
      __hip_atomic_store(&flags[bid], (unsigned)(t + 1), __ATOMIC_RELAXED,
                         __HIP_MEMORY_SCOPE_AGENT);
  }
  *(float2*)(c_ws + (size_t)(grp * 16 + ub) * HSZ + jt * 32 + uj) = creg;
}

// ---------------- phase 3: out = h_last @ W_lin^T + b_lin ----------------
__global__ void final_kernel(const float* __restrict__ hfin, const float* __restrict__ Wlin,
                             const float* __restrict__ blin, float* __restrict__ out) {
  int b = blockIdx.x;
  int l = threadIdx.x;  // 64 threads = 1 wave
  float s = 0.f;
#pragma unroll
  for (int k = 0; k < 8; ++k) s += hfin[(size_t)b * HSZ + k * 64 + l] * Wlin[k * 64 + l];
  for (int off = 32; off; off >>= 1) s += __shfl_down(s, off);
  if (l == 0) out[b] = s + blin[0];
}

extern "C" void kernel_launch(void* const* d_in, const int* in_sizes, int n_in,
                              void* d_out, int out_size, void* d_ws, size_t ws_size,
                              hipStream_t stream) {
  const float* x = (const float*)d_in[0];
  const float* Wih = (const float*)d_in[1];
  const float* Whh = (const float*)d_in[2];
  const float* bih = (const float*)d_in[3];
  const float* bhh = (const float*)d_in[4];
  const float* Wlin = (const float*)d_in[5];
  const float* blin = (const float*)d_in[6];
  float* out = (float*)d_out;

  char* ws = (char*)d_ws;
  size_t off = 0;
  auto alloc = [&](size_t sz) {
    char* p = ws + off;
    off += (sz + 255) & ~(size_t)255;
    return p;
  };
  unsigned* flags = (unsigned*)alloc(4096);
  short* hbuf = (short*)alloc((size_t)2 * BATCH_N * HSZ * 2);
  float* c_ws = (float*)alloc((size_t)BATCH_N * HSZ * 4);
  size_t zero_bytes = off;  // flags + hbuf + c_ws zeroed every launch (replay reset)
  float* hfin = (float*)alloc((size_t)BATCH_N * HSZ * 4);
  float* bias = (float*)alloc((size_t)G4 * 4);
  short* Wih_bf = (short*)alloc((size_t)G4 * ISZ * 2);
  short* Whh_bf = (short*)alloc((size_t)G4 * HSZ * 2);
  size_t fixed = off;

  int Tc = SEQ_T;
  while (Tc > 32 && fixed + (size_t)Tc * 8 * 16 * 2048 * 2 > ws_size) Tc >>= 1;
  short* XP = (short*)alloc((size_t)Tc * 8 * 16 * 2048 * 2);
  (void)n_in; (void)in_sizes; (void)out_size;

  hipMemsetAsync(d_ws, 0, zero_bytes, stream);
  prep_kernel<<<1024, 256, 0, stream>>>(Wih, Whh, bih, bhh, Wih_bf, Whh_bf, bias);

  int MS = 2;
  while (Tc * MS < 256) MS <<= 1;
  if (MS > 32) MS = 32;
  int M_TILE = G4 / MS;

  const size_t lds1 = 65536 + 32768;          // 96KB
  const size_t lds2 = 131072 + 16384 + 8192;  // 152KB

  for (int t0 = 0; t0 < SEQ_T; t0 += Tc) {
    xproj_kernel<<<dim3(Tc * MS), dim3(256), lds1, stream>>>(x, Wih_bf, bias, XP, t0, Tc, M_TILE);
    rec_kernel<<<dim3(128), dim3(256), lds2, stream>>>(XP, Whh_bf, hbuf, c_ws, hfin, flags,
                                                       t0, Tc, SEQ_T);
  }
  final_kernel<<<dim3(BATCH_N), dim3(64), 0, stream>>>(hfin, Wlin, blin, out);
}

// Round 2
// 2529.990 us; speedup vs baseline: 1.0578x; 1.0578x over previous
//
#include <hip/hip_runtime.h>

#define SEQ_T 512
#define BATCH_N 128
#define ISZ 256
#define HSZ 512
#define G4 2048  // 4*HSZ

typedef __attribute__((ext_vector_type(8))) short short8;
typedef __attribute__((ext_vector_type(4))) float f32x4;
typedef __attribute__((ext_vector_type(4))) unsigned int u32x4;

__device__ __forceinline__ unsigned short f2bf(float f) {
  unsigned u = __builtin_bit_cast(unsigned, f);
  u = u + 0x7FFFu + ((u >> 16) & 1u);
  return (unsigned short)(u >> 16);
}
__device__ __forceinline__ float bf2f(unsigned short s) {
  unsigned u = ((unsigned)s) << 16;
  return __builtin_bit_cast(float, u);
}
__device__ __forceinline__ float sigm(float x) {
  x = fminf(fmaxf(x, -30.f), 30.f);
  return 1.f / (1.f + __expf(-x));
}
__device__ __forceinline__ float tanh_f(float x) {
  x = fminf(fmaxf(x, -15.f), 15.f);
  float e = __expf(2.f * x);
  return (e - 1.f) / (e + 1.f);
}

// ---- coherent (LLC) wide access primitives: bypass L1 + per-XCD L2 ----
__device__ __forceinline__ u32x4 ld_coh16(const void* p) {
  u32x4 v;
  asm volatile("global_load_dwordx4 %0, %1, off sc0 sc1" : "=v"(v) : "v"(p));
  return v;
}
__device__ __forceinline__ void st_coh16(void* p, u32x4 v) {
  asm volatile("global_store_dwordx4 %0, %1, off sc0 sc1" : : "v"(p), "v"(v) : "memory");
}
__device__ __forceinline__ void wait_vm0() {
  asm volatile("s_waitcnt vmcnt(0)" ::: "memory");
  __builtin_amdgcn_sched_barrier(0);
}

// ---------------- prep: f32 -> bf16 weights, bias sum ----------------
__global__ void prep_kernel(const float* __restrict__ Wih_f, const float* __restrict__ Whh_f,
                            const float* __restrict__ bih, const float* __restrict__ bhh,
                            short* __restrict__ Wih_bf, short* __restrict__ Whh_bf,
                            float* __restrict__ bias) {
  int stride = gridDim.x * blockDim.x;
  int i0 = blockIdx.x * blockDim.x + threadIdx.x;
  for (int i = i0; i < G4 * HSZ; i += stride) Whh_bf[i] = (short)f2bf(Whh_f[i]);
  for (int i = i0; i < G4 * ISZ; i += stride) Wih_bf[i] = (short)f2bf(Wih_f[i]);
  for (int i = i0; i < G4; i += stride) bias[i] = bih[i] + bhh[i];
}

// ---------------- phase 1: x_proj GEMM (bf16 MFMA) ----------------
__global__ __launch_bounds__(256) void xproj_kernel(
    const float* __restrict__ x, const short* __restrict__ Wih,
    const float* __restrict__ bias, short* __restrict__ XP,
    int t0, int Tc, int M_TILE) {
  extern __shared__ char smem[];
  short* Xl = (short*)smem;             // [128][256] bf16, swizzled
  short* Wt = (short*)(smem + 65536);   // [64][256] bf16, swizzled
  const int tid = threadIdx.x;
  const int tl = blockIdx.x % Tc;
  const int ms = blockIdx.x / Tc;
  const int t = t0 + tl;
  const int m0 = ms * M_TILE;
  const int w = tid >> 6, lane = tid & 63, lo = lane & 15, hi = lane >> 4;

  for (int idx = tid; idx < BATCH_N * 64; idx += 256) {
    int b = idx >> 6, q = idx & 63;
    const float4 v = *(const float4*)(x + ((size_t)b * SEQ_T + t) * ISZ + q * 4);
    unsigned long long p = (unsigned long long)f2bf(v.x)
        | ((unsigned long long)f2bf(v.y) << 16)
        | ((unsigned long long)f2bf(v.z) << 32)
        | ((unsigned long long)f2bf(v.w) << 48);
    int byte = (b * 512 + q * 8) ^ ((b & 7) << 4);
    *(unsigned long long*)((char*)Xl + byte) = p;
  }
  __syncthreads();

  for (int mi = 0; mi < M_TILE / 64; ++mi) {
    int g0 = m0 + mi * 64;
    for (int idx = tid; idx < 64 * 32; idx += 256) {
      int r = idx >> 5, q = idx & 31;
      short8 v = *(const short8*)(Wih + (size_t)(g0 + r) * ISZ + q * 8);
      int byte = (r * 512 + q * 16) ^ ((r & 7) << 4);
      *(short8*)((char*)Wt + byte) = v;
    }
    __syncthreads();

    f32x4 acc[8];
#pragma unroll
    for (int n = 0; n < 8; ++n) acc[n] = (f32x4){0.f, 0.f, 0.f, 0.f};
    const int rA = w * 16 + lo;
#pragma unroll
    for (int ks = 0; ks < 8; ++ks) {
      int kb = ks * 64 + hi * 16;
      short8 a = *(const short8*)((const char*)Wt + ((rA * 512 + kb) ^ ((rA & 7) << 4)));
#pragma unroll
      for (int n = 0; n < 8; ++n) {
        int rB = n * 16 + lo;
        short8 bb = *(const short8*)((const char*)Xl + ((rB * 512 + kb) ^ ((rB & 7) << 4)));
        acc[n] = __builtin_amdgcn_mfma_f32_16x16x32_bf16(a, bb, acc[n], 0, 0, 0);
      }
    }
    float b4[4];
#pragma unroll
    for (int r = 0; r < 4; ++r) b4[r] = bias[g0 + w * 16 + hi * 4 + r];
#pragma unroll
    for (int n = 0; n < 8; ++n) {
#pragma unroll
      for (int r = 0; r < 4; ++r) {
        int g = g0 + w * 16 + hi * 4 + r;
        float v = acc[n][r] + b4[r];
        int jloc = g & (HSZ - 1);
        int gate = g >> 9;
        int jtl = jloc >> 5;
        int j = jloc & 31;
        size_t blk = ((size_t)tl * 8 + n) * 16 + jtl;
        size_t oidx = blk * 2048 +
            (size_t)(((gate * 4 + ((j >> 2) & 3)) * 16 + lo) * 8 + ((j >> 4) * 4) + (j & 3));
        XP[oidx] = (short)f2bf(v);
      }
    }
    __syncthreads();
  }
}

// ---------------- phase 2: persistent recurrence ----------------
// grid = 128 wgs: grp = bid>>4 (16 batches), jt = bid&15 (32 hidden units).
__global__ __launch_bounds__(256) void rec_kernel(
    const short* __restrict__ XP, const short* __restrict__ Whh,
    short* __restrict__ hbuf, float* __restrict__ c_ws, float* __restrict__ hfin,
    unsigned int* __restrict__ flags, int t0, int Tc, int Ttot) {
  extern __shared__ char smem[];
  short* Wl = (short*)smem;                        // [128][512] bf16 swizzled (128KB)
  short* Hl = (short*)(smem + 131072);             // [16][512] bf16 swizzled (16KB)
  float* actsL = (float*)(smem + 131072 + 16384);  // [4][32][16] f32 (8KB)
  unsigned* hout = (unsigned*)(smem + 131072 + 16384 + 8192);  // [16][16] u32 (1KB)
  const int tid = threadIdx.x;
  const int bid = blockIdx.x;
  const int grp = bid >> 4;
  const int jt = bid & 15;
  const int w = tid >> 6, lane = tid & 63, lo = lane & 15, hi = lane >> 4;

  // stage W_hh slice: row r = gate(r>>5)*512 + jt*32 + (r&31)
  for (int idx = tid; idx < 128 * 64; idx += 256) {
    int r = idx >> 6, q = idx & 63;
    int g = (r >> 5) * HSZ + jt * 32 + (r & 31);
    short8 v = *(const short8*)(Whh + (size_t)g * HSZ + q * 8);
    int byte = (r * 1024 + q * 16) ^ ((r & 7) << 4);
    *(short8*)((char*)Wl + byte) = v;
  }
  const int ub = tid >> 4;        // batch_loc 0..15
  const int uj = (tid & 15) * 2;  // j0 (2 consecutive j per thread)
  float2 creg = *(const float2*)(c_ws + (size_t)(grp * 16 + ub) * HSZ + jt * 32 + uj);
  __syncthreads();

  short8 xp_cur;
  {
    size_t blk = ((size_t)0 * 8 + grp) * 16 + jt;
    xp_cur = *(const short8*)(XP + blk * 2048 + tid * 8);
  }

  for (int tl = 0; tl < Tc; ++tl) {
    const int t = t0 + tl;
    if (t > 0 && tid < 16) {
      const unsigned tgt = (unsigned)t;
      while (__hip_atomic_load(&flags[(grp * 16 + tid) * 32], __ATOMIC_RELAXED,
                               __HIP_MEMORY_SCOPE_AGENT) < tgt) {}
    }
    __syncthreads();  // B1

    // stage h tile into LDS (coherent wide loads, 64B/thread)
    if (t == 0) {
      for (int idx = tid; idx < 2048; idx += 256) {
        int r = idx >> 7, q = idx & 127;
        int byte = (r * 1024 + q * 8) ^ ((r & 7) << 4);
        *(unsigned long long*)((char*)Hl + byte) = 0ULL;
      }
    } else {
      const char* src = (const char*)hbuf +
          ((size_t)(t & 1) * BATCH_N * HSZ + (size_t)grp * 16 * HSZ) * 2;
      int bl = tid >> 4, seg = tid & 15;
      const char* rp = src + bl * 1024 + seg * 64;
      u32x4 v0 = ld_coh16(rp);
      u32x4 v1 = ld_coh16(rp + 16);
      u32x4 v2 = ld_coh16(rp + 32);
      u32x4 v3 = ld_coh16(rp + 48);
      wait_vm0();
      int base = bl * 1024 + seg * 64;
      int sw = (bl & 7) << 4;
      *(u32x4*)((char*)Hl + ((base + 0) ^ sw)) = v0;
      *(u32x4*)((char*)Hl + ((base + 16) ^ sw)) = v1;
      *(u32x4*)((char*)Hl + ((base + 32) ^ sw)) = v2;
      *(u32x4*)((char*)Hl + ((base + 48) ^ sw)) = v3;
    }
    __syncthreads();  // B2

    f32x4 acc0 = {0.f, 0.f, 0.f, 0.f}, acc1 = {0.f, 0.f, 0.f, 0.f};
    const int rA0 = w * 32 + lo;
#pragma unroll
    for (int ks = 0; ks < 16; ++ks) {
      int kb = ks * 64 + hi * 16;
      short8 a0 = *(const short8*)((const char*)Wl + ((rA0 * 1024 + kb) ^ ((rA0 & 7) << 4)));
      short8 a1 = *(const short8*)((const char*)Wl + (((rA0 + 16) * 1024 + kb) ^ ((rA0 & 7) << 4)));
      short8 bf = *(const short8*)((const char*)Hl + ((lo * 1024 + kb) ^ ((lo & 7) << 4)));
      acc0 = __builtin_amdgcn_mfma_f32_16x16x32_bf16(a0, bf, acc0, 0, 0, 0);
      acc1 = __builtin_amdgcn_mfma_f32_16x16x32_bf16(a1, bf, acc1, 0, 0, 0);
    }

    // activations -> LDS
#pragma unroll
    for (int m = 0; m < 2; ++m) {
      f32x4 av = m ? acc1 : acc0;
#pragma unroll
      for (int r = 0; r < 4; ++r) {
        float pre = av[r] + bf2f((unsigned short)xp_cur[m * 4 + r]);
        float a = (w == 2) ? tanh_f(pre) : sigm(pre);
        int j = m * 16 + hi * 4 + r;
        actsL[(w * 32 + j) * 16 + lo] = a;
      }
    }
    if (tl + 1 < Tc) {
      size_t blk = ((size_t)(tl + 1) * 8 + grp) * 16 + jt;
      xp_cur = *(const short8*)(XP + blk * 2048 + tid * 8);
    }
    __syncthreads();  // B3

    // c/h update: this thread owns (b=ub, j=uj..uj+1)
    {
      float ig0 = actsL[(0 * 32 + uj) * 16 + ub], fg0 = actsL[(1 * 32 + uj) * 16 + ub];
      float gg0 = actsL[(2 * 32 + uj) * 16 + ub], og0 = actsL[(3 * 32 + uj) * 16 + ub];
      float ig1 = actsL[(0 * 32 + uj + 1) * 16 + ub], fg1 = actsL[(1 * 32 + uj + 1) * 16 + ub];
      float gg1 = actsL[(2 * 32 + uj + 1) * 16 + ub], og1 = actsL[(3 * 32 + uj + 1) * 16 + ub];
      creg.x = fg0 * creg.x + ig0 * gg0;
      creg.y = fg1 * creg.y + ig1 * gg1;
      float h0 = og0 * tanh_f(creg.x);
      float h1 = og1 * tanh_f(creg.y);
      unsigned hp = (unsigned)f2bf(h0) | ((unsigned)f2bf(h1) << 16);
      hout[tid] = hp;  // hout[ub][uj/2]
      if (t == Ttot - 1) {
        float2 hv;
        hv.x = h0; hv.y = h1;
        *(float2*)(hfin + (size_t)(grp * 16 + ub) * HSZ + jt * 32 + uj) = hv;
      }
    }
    __syncthreads();  // B4

    // wave 0 publishes h slice (1KB) with coherent wide stores, then flag
    if (tid < 64) {
      int b = tid >> 2, q4 = tid & 3;
      u32x4 hv = *(const u32x4*)((const char*)hout + b * 64 + q4 * 16);
      char* dst = (char*)hbuf +
          ((size_t)((t + 1) & 1) * BATCH_N * HSZ + (size_t)(grp * 16 + b) * HSZ + jt * 32) * 2 +
          q4 * 16;
      st_coh16(dst, hv);
      wait_vm0();
      if (tid == 0)
        __hip_atomic_store(&flags[bid * 32], (unsigned)(t + 1), __ATOMIC_RELAXED,
                           __HIP_MEMORY_SCOPE_AGENT);
    }
  }
  *(float2*)(c_ws + (size_t)(grp * 16 + ub) * HSZ + jt * 32 + uj) = creg;
}

// ---------------- phase 3: out = h_last @ W_lin^T + b_lin ----------------
__global__ void final_kernel(const float* __restrict__ hfin, const float* __restrict__ Wlin,
                             const float* __restrict__ blin, float* __restrict__ out) {
  int b = blockIdx.x;
  int l = threadIdx.x;  // 64 threads = 1 wave
  float s = 0.f;
#pragma unroll
  for (int k = 0; k < 8; ++k) s += hfin[(size_t)b * HSZ + k * 64 + l] * Wlin[k * 64 + l];
  for (int off = 32; off; off >>= 1) s += __shfl_down(s, off);
  if (l == 0) out[b] = s + blin[0];
}

extern "C" void kernel_launch(void* const* d_in, const int* in_sizes, int n_in,
                              void* d_out, int out_size, void* d_ws, size_t ws_size,
                              hipStream_t stream) {
  const float* x = (const float*)d_in[0];
  const float* Wih = (const float*)d_in[1];
  const float* Whh = (const float*)d_in[2];
  const float* bih = (const float*)d_in[3];
  const float* bhh = (const float*)d_in[4];
  const float* Wlin = (const float*)d_in[5];
  const float* blin = (const float*)d_in[6];
  float* out = (float*)d_out;

  char* ws = (char*)d_ws;
  size_t off = 0;
  auto alloc = [&](size_t sz) {
    char* p = ws + off;
    off += (sz + 255) & ~(size_t)255;
    return p;
  };
  unsigned* flags = (unsigned*)alloc(128 * 128);  // 128B-padded per producer
  short* hbuf = (short*)alloc((size_t)2 * BATCH_N * HSZ * 2);
  float* c_ws = (float*)alloc((size_t)BATCH_N * HSZ * 4);
  size_t zero_bytes = off;  // flags + hbuf + c_ws zeroed every launch (replay reset)
  float* hfin = (float*)alloc((size_t)BATCH_N * HSZ * 4);
  float* bias = (float*)alloc((size_t)G4 * 4);
  short* Wih_bf = (short*)alloc((size_t)G4 * ISZ * 2);
  short* Whh_bf = (short*)alloc((size_t)G4 * HSZ * 2);
  size_t fixed = off;

  int Tc = SEQ_T;
  while (Tc > 32 && fixed + (size_t)Tc * 8 * 16 * 2048 * 2 > ws_size) Tc >>= 1;
  short* XP = (short*)alloc((size_t)Tc * 8 * 16 * 2048 * 2);
  (void)n_in; (void)in_sizes; (void)out_size;

  hipMemsetAsync(d_ws, 0, zero_bytes, stream);
  prep_kernel<<<1024, 256, 0, stream>>>(Wih, Whh, bih, bhh, Wih_bf, Whh_bf, bias);

  int MS = 2;
  while (Tc * MS < 256) MS <<= 1;
  if (MS > 32) MS = 32;
  int M_TILE = G4 / MS;

  const size_t lds1 = 65536 + 32768;                 // 96KB
  const size_t lds2 = 131072 + 16384 + 8192 + 1024;  // 153KB

  for (int t0 = 0; t0 < SEQ_T; t0 += Tc) {
    xproj_kernel<<<dim3(Tc * MS), dim3(256), lds1, stream>>>(x, Wih_bf, bias, XP, t0, Tc, M_TILE);
    rec_kernel<<<dim3(128), dim3(256), lds2, stream>>>(XP, Whh_bf, hbuf, c_ws, hfin, flags,
                                                       t0, Tc, SEQ_T);
  }
  final_kernel<<<dim3(BATCH_N), dim3(64), 0, stream>>>(hfin, Wlin, blin, out);
}

// Round 3
// 1879.483 us; speedup vs baseline: 1.4239x; 1.3461x over previous
//
#include <hip/hip_runtime.h>

#define SEQ_T 512
#define BATCH_N 128
#define ISZ 256
#define HSZ 512
#define G4 2048  // 4*HSZ
#define HSLOT (BATCH_N * HSZ * 2)  // 131072 bytes per h step-slot

typedef __attribute__((ext_vector_type(8))) short short8;
typedef __attribute__((ext_vector_type(4))) float f32x4;
typedef __attribute__((ext_vector_type(4))) unsigned int u32x4;

__device__ __forceinline__ unsigned short f2bf(float f) {
  unsigned u = __builtin_bit_cast(unsigned, f);
  u = u + 0x7FFFu + ((u >> 16) & 1u);
  return (unsigned short)(u >> 16);
}
__device__ __forceinline__ float bf2f(unsigned short s) {
  unsigned u = ((unsigned)s) << 16;
  return __builtin_bit_cast(float, u);
}
__device__ __forceinline__ float sigm(float x) {
  x = fminf(fmaxf(x, -30.f), 30.f);
  return 1.f / (1.f + __expf(-x));
}
__device__ __forceinline__ float tanh_f(float x) {
  x = fminf(fmaxf(x, -15.f), 15.f);
  float e = __expf(2.f * x);
  return (e - 1.f) / (e + 1.f);
}

// ---- coherent (LLC) access primitives: bypass L1 + per-XCD L2 ----
__device__ __forceinline__ u32x4 ld_coh16(const void* p) {
  u32x4 v;
  asm volatile("global_load_dwordx4 %0, %1, off sc0 sc1" : "=v"(v) : "v"(p));
  return v;
}
__device__ __forceinline__ void st_coh4(void* p, unsigned v) {
  asm volatile("global_store_dword %0, %1, off sc0 sc1" : : "v"(p), "v"(v) : "memory");
}
__device__ __forceinline__ void wait_vm0() {
  asm volatile("s_waitcnt vmcnt(0)" ::: "memory");
  __builtin_amdgcn_sched_barrier(0);
}
__device__ __forceinline__ bool anyz(u32x4 v) {
  return (v[0] == 0u) || (v[1] == 0u) || (v[2] == 0u) || (v[3] == 0u);
}

// ---------------- prep: f32 -> bf16 weights, bias sum ----------------
__global__ void prep_kernel(const float* __restrict__ Wih_f, const float* __restrict__ Whh_f,
                            const float* __restrict__ bih, const float* __restrict__ bhh,
                            short* __restrict__ Wih_bf, short* __restrict__ Whh_bf,
                            float* __restrict__ bias) {
  int stride = gridDim.x * blockDim.x;
  int i0 = blockIdx.x * blockDim.x + threadIdx.x;
  for (int i = i0; i < G4 * HSZ; i += stride) Whh_bf[i] = (short)f2bf(Whh_f[i]);
  for (int i = i0; i < G4 * ISZ; i += stride) Wih_bf[i] = (short)f2bf(Wih_f[i]);
  for (int i = i0; i < G4; i += stride) bias[i] = bih[i] + bhh[i];
}

// ---------------- fused persistent recurrence (x-proj folded into K-loop) ----
// grid = 128 wgs: grp = bid>>4 (16 batches), jt = bid&15 (32 hidden units).
// Wave w handles gate w (0=i,1=f,2=g,3=o). W_hh and W_ih slices in registers.
__global__ __launch_bounds__(256, 1) void rec_kernel(
    const float* __restrict__ x, const short* __restrict__ Wih,
    const short* __restrict__ Whh, const float* __restrict__ bias,
    char* __restrict__ hbufs, unsigned int* __restrict__ flags,
    float* __restrict__ hfin) {
  __shared__ char smemH[16384];   // h tile [16][512] bf16, XOR-swizzled
  __shared__ char smemX[8192];    // x tile [16][256] bf16, XOR-swizzled
  __shared__ float actsL[2048];   // [4 gates][32 j][16 b] f32

  const int tid = threadIdx.x;
  const int bid = blockIdx.x;
  const int grp = bid >> 4;
  const int jt = bid & 15;
  const int w = tid >> 6, lane = tid & 63, lo = lane & 15, hi = lane >> 4;
  const int ub = tid >> 4;        // batch_loc 0..15 (c/h update, x stage, h poll)
  const int seg = tid & 15;       // 64B segment / producer index
  const int uj = seg * 2;         // j0 for c/h update

  // ---- weight fragments into registers ----
  // A-frag rows: block0 -> gate rows (w*512 + jt*32 + lo), block1 -> +16
  short8 wh0[16], wh1[16], wx0[8], wx1[8];
  {
    const short* b0 = Whh + (size_t)(w * HSZ + jt * 32 + lo) * HSZ + hi * 8;
    const short* b1 = b0 + 16 * HSZ;
#pragma unroll
    for (int ks = 0; ks < 16; ++ks) {
      wh0[ks] = *(const short8*)(b0 + ks * 32);
      wh1[ks] = *(const short8*)(b1 + ks * 32);
    }
    const short* c0 = Wih + (size_t)(w * HSZ + jt * 32 + lo) * ISZ + hi * 8;
    const short* c1 = c0 + 16 * ISZ;
#pragma unroll
    for (int ks = 0; ks < 8; ++ks) {
      wx0[ks] = *(const short8*)(c0 + ks * 32);
      wx1[ks] = *(const short8*)(c1 + ks * 32);
    }
  }
  float b4a[4], b4b[4];
#pragma unroll
  for (int r = 0; r < 4; ++r) {
    b4a[r] = bias[w * HSZ + jt * 32 + hi * 4 + r];
    b4b[r] = bias[w * HSZ + jt * 32 + 16 + hi * 4 + r];
  }

  // ---- x staging: this thread owns batch ub, elements xq*16..+15 ----
  const int xq = seg;
  const float* xrow = x + (size_t)(grp * 16 + ub) * SEQ_T * ISZ + xq * 16;
  const int xbase = ub * 512 + xq * 32;
  const int xsw = (ub & 7) << 4;
  {
    // stage x(0) directly
    float4 a0 = *(const float4*)(xrow + 0);
    float4 a1 = *(const float4*)(xrow + 4);
    float4 a2 = *(const float4*)(xrow + 8);
    float4 a3 = *(const float4*)(xrow + 12);
    u32x4 p0, p1;
    p0[0] = f2bf(a0.x) | ((unsigned)f2bf(a0.y) << 16);
    p0[1] = f2bf(a0.z) | ((unsigned)f2bf(a0.w) << 16);
    p0[2] = f2bf(a1.x) | ((unsigned)f2bf(a1.y) << 16);
    p0[3] = f2bf(a1.z) | ((unsigned)f2bf(a1.w) << 16);
    p1[0] = f2bf(a2.x) | ((unsigned)f2bf(a2.y) << 16);
    p1[1] = f2bf(a2.z) | ((unsigned)f2bf(a2.w) << 16);
    p1[2] = f2bf(a3.x) | ((unsigned)f2bf(a3.y) << 16);
    p1[3] = f2bf(a3.z) | ((unsigned)f2bf(a3.w) << 16);
    *(u32x4*)(smemX + ((xbase + 0) ^ xsw)) = p0;
    *(u32x4*)(smemX + ((xbase + 16) ^ xsw)) = p1;
  }
  float4 xr0 = *(const float4*)(xrow + ISZ + 0);   // prefetch x(1)
  float4 xr1 = *(const float4*)(xrow + ISZ + 4);
  float4 xr2 = *(const float4*)(xrow + ISZ + 8);
  float4 xr3 = *(const float4*)(xrow + ISZ + 12);

  // zero h tile for t=0
  for (int i = tid; i < 1024; i += 256) ((u32x4*)smemH)[i] = (u32x4){0u, 0u, 0u, 0u};

  float cx = 0.f, cy = 0.f;

  for (int t = 0; t < SEQ_T; ++t) {
    // ---- acquire h(t): poll directly on data (single LLC round trip) ----
    if (t > 0) {
      const char* rp = hbufs + (size_t)t * HSLOT +
                       ((size_t)(grp * 16 + ub) * HSZ + seg * 32) * 2;
      u32x4 v0, v1, v2, v3;
      int spin = 0;
      for (;;) {
        v0 = ld_coh16(rp);
        v1 = ld_coh16(rp + 16);
        v2 = ld_coh16(rp + 32);
        v3 = ld_coh16(rp + 48);
        wait_vm0();
        if (!(anyz(v0) || anyz(v1) || anyz(v2) || anyz(v3))) break;
        if (++spin > 2048) {
          // fallback: legit-zero h values — confirm via producer flag, reload
          if (__hip_atomic_load(&flags[(grp * 16 + seg) * 32], __ATOMIC_RELAXED,
                                __HIP_MEMORY_SCOPE_AGENT) >= (unsigned)t) {
            v0 = ld_coh16(rp);
            v1 = ld_coh16(rp + 16);
            v2 = ld_coh16(rp + 32);
            v3 = ld_coh16(rp + 48);
            wait_vm0();
            break;
          }
          spin = 0;
        }
      }
      int base = ub * 1024 + seg * 64;
      int sw = (ub & 7) << 4;
      *(u32x4*)(smemH + ((base + 0) ^ sw)) = v0;
      *(u32x4*)(smemH + ((base + 16) ^ sw)) = v1;
      *(u32x4*)(smemH + ((base + 32) ^ sw)) = v2;
      *(u32x4*)(smemH + ((base + 48) ^ sw)) = v3;
    }
    __syncthreads();  // B_a
    // lagged flag: own h(t) stores were drained by this step's poll waits
    if (t > 0 && tid == 0)
      __hip_atomic_store(&flags[bid * 32], (unsigned)t, __ATOMIC_RELAXED,
                         __HIP_MEMORY_SCOPE_AGENT);

    // ---- gates = W_hh·h + W_ih·x + bias (K = 512 + 256) ----
    f32x4 acc0 = {0.f, 0.f, 0.f, 0.f}, acc1 = {0.f, 0.f, 0.f, 0.f};
    const int hrow = lo * 1024, hsw = (lo & 7) << 4;
#pragma unroll
    for (int ks = 0; ks < 16; ++ks) {
      short8 bf = *(const short8*)(smemH + ((hrow + ks * 64 + hi * 16) ^ hsw));
      acc0 = __builtin_amdgcn_mfma_f32_16x16x32_bf16(wh0[ks], bf, acc0, 0, 0, 0);
      acc1 = __builtin_amdgcn_mfma_f32_16x16x32_bf16(wh1[ks], bf, acc1, 0, 0, 0);
    }
    const int xrowb = lo * 512, xswr = (lo & 7) << 4;
#pragma unroll
    for (int ks = 0; ks < 8; ++ks) {
      short8 xf = *(const short8*)(smemX + ((xrowb + ks * 64 + hi * 16) ^ xswr));
      acc0 = __builtin_amdgcn_mfma_f32_16x16x32_bf16(wx0[ks], xf, acc0, 0, 0, 0);
      acc1 = __builtin_amdgcn_mfma_f32_16x16x32_bf16(wx1[ks], xf, acc1, 0, 0, 0);
    }

    // ---- activations -> LDS ----
#pragma unroll
    for (int r = 0; r < 4; ++r) {
      float p0 = acc0[r] + b4a[r];
      float p1 = acc1[r] + b4b[r];
      float a0v = (w == 2) ? tanh_f(p0) : sigm(p0);
      float a1v = (w == 2) ? tanh_f(p1) : sigm(p1);
      actsL[(w * 32 + hi * 4 + r) * 16 + lo] = a0v;
      actsL[(w * 32 + 16 + hi * 4 + r) * 16 + lo] = a1v;
    }
    __syncthreads();  // B_b

    // ---- c/h update: this thread owns (b=ub, j=uj..uj+1) ----
    {
      float ig0 = actsL[(0 * 32 + uj) * 16 + ub], fg0 = actsL[(1 * 32 + uj) * 16 + ub];
      float gg0 = actsL[(2 * 32 + uj) * 16 + ub], og0 = actsL[(3 * 32 + uj) * 16 + ub];
      float ig1 = actsL[(0 * 32 + uj + 1) * 16 + ub], fg1 = actsL[(1 * 32 + uj + 1) * 16 + ub];
      float gg1 = actsL[(2 * 32 + uj + 1) * 16 + ub], og1 = actsL[(3 * 32 + uj + 1) * 16 + ub];
      cx = fg0 * cx + ig0 * gg0;
      cy = fg1 * cy + ig1 * gg1;
      float h0 = og0 * tanh_f(cx);
      float h1 = og1 * tanh_f(cy);
      if (t < SEQ_T - 1) {
        unsigned hp = (unsigned)f2bf(h0) | ((unsigned)f2bf(h1) << 16);
        char* dst = hbufs + (size_t)(t + 1) * HSLOT +
                    ((size_t)(grp * 16 + ub) * HSZ + jt * 32 + uj) * 2;
        st_coh4(dst, hp);  // fire-and-forget; acked by next step's poll waits
      } else {
        float2 hv;
        hv.x = h0;
        hv.y = h1;
        *(float2*)(hfin + (size_t)(grp * 16 + ub) * HSZ + jt * 32 + uj) = hv;
      }
    }

    // ---- stage x(t+1) from regs; prefetch x(t+2) ----
    if (t < SEQ_T - 1) {
      u32x4 p0, p1;
      p0[0] = f2bf(xr0.x) | ((unsigned)f2bf(xr0.y) << 16);
      p0[1] = f2bf(xr0.z) | ((unsigned)f2bf(xr0.w) << 16);
      p0[2] = f2bf(xr1.x) | ((unsigned)f2bf(xr1.y) << 16);
      p0[3] = f2bf(xr1.z) | ((unsigned)f2bf(xr1.w) << 16);
      p1[0] = f2bf(xr2.x) | ((unsigned)f2bf(xr2.y) << 16);
      p1[1] = f2bf(xr2.z) | ((unsigned)f2bf(xr2.w) << 16);
      p1[2] = f2bf(xr3.x) | ((unsigned)f2bf(xr3.y) << 16);
      p1[3] = f2bf(xr3.z) | ((unsigned)f2bf(xr3.w) << 16);
      *(u32x4*)(smemX + ((xbase + 0) ^ xsw)) = p0;
      *(u32x4*)(smemX + ((xbase + 16) ^ xsw)) = p1;
      if (t < SEQ_T - 2) {
        const float* xp = xrow + (size_t)(t + 2) * ISZ;
        xr0 = *(const float4*)(xp + 0);
        xr1 = *(const float4*)(xp + 4);
        xr2 = *(const float4*)(xp + 8);
        xr3 = *(const float4*)(xp + 12);
      }
    }
    // no barrier needed here: next step's smemH/actsL writes are ordered by B_a/B_b
  }
}

// ---------------- out = h_last @ W_lin^T + b_lin ----------------
__global__ void final_kernel(const float* __restrict__ hfin, const float* __restrict__ Wlin,
                             const float* __restrict__ blin, float* __restrict__ out) {
  int b = blockIdx.x;
  int l = threadIdx.x;  // 64 threads = 1 wave
  float s = 0.f;
#pragma unroll
  for (int k = 0; k < 8; ++k) s += hfin[(size_t)b * HSZ + k * 64 + l] * Wlin[k * 64 + l];
  for (int off = 32; off; off >>= 1) s += __shfl_down(s, off);
  if (l == 0) out[b] = s + blin[0];
}

extern "C" void kernel_launch(void* const* d_in, const int* in_sizes, int n_in,
                              void* d_out, int out_size, void* d_ws, size_t ws_size,
                              hipStream_t stream) {
  const float* x = (const float*)d_in[0];
  const float* Wih = (const float*)d_in[1];
  const float* Whh = (const float*)d_in[2];
  const float* bih = (const float*)d_in[3];
  const float* bhh = (const float*)d_in[4];
  const float* Wlin = (const float*)d_in[5];
  const float* blin = (const float*)d_in[6];
  float* out = (float*)d_out;

  char* ws = (char*)d_ws;
  size_t off = 0;
  auto alloc = [&](size_t sz) {
    char* p = ws + off;
    off += (sz + 255) & ~(size_t)255;
    return p;
  };
  unsigned* flags = (unsigned*)alloc(128 * 32 * 4);        // 16KB, 128B/producer
  char* hbufs = (char*)alloc((size_t)SEQ_T * HSLOT);       // 64MB rotating h slots
  size_t zero_bytes = off;  // flags + hbufs zeroed every launch (replay reset)
  float* hfin = (float*)alloc((size_t)BATCH_N * HSZ * 4);
  float* bias = (float*)alloc((size_t)G4 * 4);
  short* Wih_bf = (short*)alloc((size_t)G4 * ISZ * 2);
  short* Whh_bf = (short*)alloc((size_t)G4 * HSZ * 2);
  (void)n_in; (void)in_sizes; (void)out_size; (void)ws_size;

  hipMemsetAsync(d_ws, 0, zero_bytes, stream);
  prep_kernel<<<1024, 256, 0, stream>>>(Wih, Whh, bih, bhh, Wih_bf, Whh_bf, bias);
  rec_kernel<<<dim3(128), dim3(256), 0, stream>>>(x, Wih_bf, Whh_bf, bias, hbufs, flags, hfin);
  final_kernel<<<dim3(BATCH_N), dim3(64), 0, stream>>>(hfin, Wlin, blin, out);
}